// Round 7
// baseline (396.080 us; speedup 1.0000x reference)
//
#include <hip/hip_runtime.h>
#include <stdint.h>

#define GRID_Z 10
#define GRID_Y 400
#define GRID_X 352
#define NGRID (GRID_Z * GRID_Y * GRID_X)   // 1,408,000
#define NVOX 200000
#define CCH 128
#define MROI 64
#define GXD 64
#define GYD 32
#define GZD 4
#define GCELLS 8192                         // GXD*GYD*GZD
#define NTAPS 147                           // 7*7*3
#define FPAD 132                            // feat LDS row pitch (128+4)
#define TROWS 64                            // voxel rows per tile
#define DYN_LDS (GCELLS * 4 + TROWS * FPAD * 4 + TROWS * 4)   // 66816 B

// Recompute a grid cell's world xyz exactly like the reference (fp32, no fma
// contraction so floor() boundaries match XLA's mul+add evaluation).
__device__ __forceinline__ void cell_xyz(const float* __restrict__ roi, int g,
                                         float& X, float& Y, float& Z) {
#pragma clang fp contract(off)
    int iz = g & 3;
    int iy = (g >> 2) & 31;
    int ix = g >> 7;
    float bx = roi[3] * 2.0f;   // EXTEND on x,y dims
    float by = roi[4] * 2.0f;
    float bz = roi[5];
    float lx = (ix + 0.5f) / 64.0f * bx - bx / 2.0f;
    float ly = (iy + 0.5f) / 32.0f * by - by / 2.0f;
    float lz = (iz + 0.5f) / 4.0f  * bz - bz / 2.0f;
    float c = cosf(roi[6]);
    float s = sinf(roi[6]);
    X = lx * c + ly * (-s) + roi[0];
    Y = lx * s + ly * c    + roi[1];
    Z = lz + roi[2];
}

__global__ void k_scatter(const int* __restrict__ vcoords, int* __restrict__ v2p,
                          int* __restrict__ cnt) {
    int i = blockIdx.x * 256 + threadIdx.x;
    if (blockIdx.x == 0 && threadIdx.x < MROI) cnt[threadIdx.x] = 0;  // fold memset
    if (i >= NVOX) return;
    int z = vcoords[i * 4 + 1];
    int y = vcoords[i * 4 + 2];
    int x = vcoords[i * 4 + 3];
    // Duplicate coords: XLA scatter applies updates in order -> last (max idx) wins.
    atomicMax(&v2p[(z * GRID_Y + y) * GRID_X + x], i);
}

// Per (m, g): map grid cell to voxel index; ballot-compact valid (p,g) pairs
// into a per-ROI list (order nondeterministic; only perturbs fp sum order).
__global__ void k_build(const float* __restrict__ rois, const int* __restrict__ v2p,
                        unsigned* __restrict__ list, int* __restrict__ cnt) {
#pragma clang fp contract(off)
    int g = blockIdx.x * 256 + threadIdx.x;   // [0, GCELLS)
    int m = blockIdx.y;
    int lane = threadIdx.x & 63;
    const float* roi = rois + m * 7;
    float X, Y, Z;
    cell_xyz(roi, g, X, Y, Z);
    float fx = floorf((X - 0.0f)     / 0.05f);
    float fy = floorf((Y - (-40.0f)) / 0.05f);
    float fz = floorf((Z - (-3.0f))  / 0.1f);
    int cx = (int)floorf(fx / 4.0f);
    int cy = (int)floorf(fy / 4.0f);
    int cz = (int)floorf(fz / 4.0f);
    int p = -1;
    if (cz >= 0 && cz < GRID_Z && cy >= 0 && cy < GRID_Y && cx >= 0 && cx < GRID_X)
        p = v2p[(cz * GRID_Y + cy) * GRID_X + cx];
    bool v = p >= 0;
    unsigned long long bal = __ballot(v);
    int nset = __popcll(bal);
    int base = 0;
    if (lane == 0 && nset) base = atomicAdd(&cnt[m], nset);
    base = __shfl(base, 0, 64);
    if (v) {
        int pos = __popcll(bal & ((1ull << lane) - 1ull));
        list[m * GCELLS + base + pos] = ((unsigned)p << 13) | (unsigned)g;
    }
}

// Batched-GEMM dots + LDS scatter. Block (s, m): private 32 KB LDS score for
// ROI m; 64-voxel tiles staged in LDS; wave w owns taps [40w,40w+40); lane
// (vi=l&7, ti=(l>>3)&7) computes an 8-voxel x 5-tap register tile over K=128
// (13 mem instr per 160 FMAs). Dots deposit via ds_add_f32; epilogue writes
// the 32 KB partial with plain coalesced stores. Dynamic LDS: 66.8 KB.
__global__ __launch_bounds__(256, 2) void k_dots(
        const float* __restrict__ vfeat, const float* __restrict__ fproto,
        const unsigned* __restrict__ list, const int* __restrict__ cnt,
        float* __restrict__ partial) {
    extern __shared__ char dynsm[];
    float*    sscore = (float*)dynsm;                          // GCELLS floats
    float*    sfeat  = (float*)(dynsm + GCELLS * 4);           // TROWS*FPAD
    unsigned* sg     = (unsigned*)(dynsm + GCELLS * 4 + TROWS * FPAD * 4);

    const int m    = blockIdx.y;
    const int NS   = gridDim.x;
    const int tid  = threadIdx.x;
    const int w    = tid >> 6;                 // wave 0..3
    const int lane = tid & 63;
    const int vi   = lane & 7;
    const int ti   = (lane >> 3) & 7;
    const int n    = cnt[m];
    const unsigned* lst = list + m * GCELLS;
    const int tbase = w * 40 + ti;             // thread's taps: tbase + 8b, b=0..4

    // hoist tap decomposition (loop-invariant)
    int tkx[5], tky[5], tkz[5], tok[5];
    #pragma unroll
    for (int b = 0; b < 5; ++b) {
        int t = tbase + 8 * b;
        tok[b] = t < NTAPS;
        int tc = tok[b] ? t : (NTAPS - 1);
        int kx  = tc / 21;
        int rem = tc - kx * 21;
        tkx[b] = kx;
        tky[b] = rem / 3;
        tkz[b] = rem - tky[b] * 3;
    }

    {   // zero the private score tile
        float4* s4 = (float4*)sscore;
        #pragma unroll
        for (int i = 0; i < GCELLS / 4 / 256; ++i)
            s4[tid + 256 * i] = make_float4(0.f, 0.f, 0.f, 0.f);
    }

    for (int vt0 = blockIdx.x * TROWS; vt0 < n; vt0 += TROWS * NS) {
        __syncthreads();                       // score-zero / prior deposits done
        {   // stage 64 feat rows: 4 threads per row, 32 floats each
            int r = tid >> 2;                  // row 0..63
            int q = tid & 3;                   // 32-float quarter
            int v = vt0 + r;
            unsigned e = 0xFFFFFFFFu;
            if (v < n) e = lst[v];
            if (q == 0) sg[r] = e;
            if (e != 0xFFFFFFFFu) {
                int p = (int)(e >> 13);
                const float4* src = (const float4*)(vfeat + (size_t)p * CCH) + q * 8;
                float4* drow = (float4*)(sfeat + r * FPAD + q * 32);
                #pragma unroll
                for (int j = 0; j < 8; ++j) drow[j] = src[j];
            }
        }
        __syncthreads();

        float acc[8][5];
        #pragma unroll
        for (int a = 0; a < 8; ++a)
            #pragma unroll
            for (int b = 0; b < 5; ++b) acc[a][b] = 0.0f;

        #pragma unroll 1
        for (int k = 0; k < CCH; k += 4) {
            float4 f[8];
            #pragma unroll
            for (int a = 0; a < 8; ++a)
                f[a] = *(const float4*)&sfeat[(vi + 8 * a) * FPAD + k];
            float4 wv[5];
            #pragma unroll
            for (int b = 0; b < 5; ++b)
                wv[b] = *(const float4*)(fproto + (tbase + (tok[b] ? 8 * b : 0)) * CCH + k);
            #pragma unroll
            for (int a = 0; a < 8; ++a)
                #pragma unroll
                for (int b = 0; b < 5; ++b) {
                    acc[a][b] = fmaf(f[a].x, wv[b].x, acc[a][b]);
                    acc[a][b] = fmaf(f[a].y, wv[b].y, acc[a][b]);
                    acc[a][b] = fmaf(f[a].z, wv[b].z, acc[a][b]);
                    acc[a][b] = fmaf(f[a].w, wv[b].w, acc[a][b]);
                }
        }

        // deposit dots into the private LDS score grid (ds_add_f32 atomics)
        #pragma unroll
        for (int b = 0; b < 5; ++b) {
            if (!tok[b]) continue;
            #pragma unroll
            for (int a = 0; a < 8; ++a) {
                unsigned e = sg[vi + 8 * a];
                if (e == 0xFFFFFFFFu) continue;
                int g  = (int)(e & 8191u);
                int cx = (g >> 7)        - (tkx[b] - 3);
                int cy = ((g >> 2) & 31) - (tky[b] - 3);
                int cz = (g & 3)         - (tkz[b] - 1);
                if ((unsigned)cx < (unsigned)GXD && (unsigned)cy < (unsigned)GYD &&
                    (unsigned)cz < (unsigned)GZD)
                    atomicAdd(&sscore[(cx << 7) | (cy << 2) | cz], acc[a][b]);
            }
        }
    }

    __syncthreads();                           // all waves' deposits done
    {   // coalesced partial writeback (covers every cell -> no global zeroing)
        float* dst = partial + ((size_t)m * NS + blockIdx.x) * GCELLS;
        const float4* s4 = (const float4*)sscore;
        float4* d4 = (float4*)dst;
        #pragma unroll
        for (int i = 0; i < GCELLS / 4 / 256; ++i)
            d4[tid + 256 * i] = s4[tid + 256 * i];
    }
}

// Fused partial-merge + argmax + output write: one block per ROI.
__global__ void k_argfin(const float* __restrict__ partial, int ns,
                         const float* __restrict__ rois,
                         const float* __restrict__ pbox,
                         float* __restrict__ out) {
    __shared__ unsigned long long red[256];
    int m = blockIdx.x;
    int tid = threadIdx.x;
    const float* base = partial + (size_t)m * ns * GCELLS;
    unsigned long long bk = 0ull;
    for (int g = tid; g < GCELLS; g += 256) {
        float v = 0.0f;
        for (int s = 0; s < ns; ++s) v += base[s * GCELLS + g];
        unsigned ub  = __float_as_uint(v);
        unsigned key = (ub & 0x80000000u) ? ~ub : (ub | 0x80000000u);  // order-preserving
        unsigned long long pk =
            ((unsigned long long)key << 32) | (unsigned)(GCELLS - 1 - g);  // ties -> smallest g
        bk = bk > pk ? bk : pk;
    }
    red[tid] = bk;
    __syncthreads();
    for (int s = 128; s > 0; s >>= 1) {
        if (tid < s) {
            unsigned long long o = red[tid + s];
            if (o > red[tid]) red[tid] = o;
        }
        __syncthreads();
    }
    if (tid == 0) {
        int g = (GCELLS - 1) - (int)(unsigned)(red[0] & 0xFFFFFFFFu);
        float X, Y, Z;
        cell_xyz(rois + m * 7, g, X, Y, Z);
        out[m * 7 + 0] = X;
        out[m * 7 + 1] = Y;
        out[m * 7 + 2] = Z;
        out[m * 7 + 3] = pbox[3];
        out[m * 7 + 4] = pbox[4];
        out[m * 7 + 5] = pbox[5];
        out[m * 7 + 6] = pbox[6];
    }
}

extern "C" void kernel_launch(void* const* d_in, const int* in_sizes, int n_in,
                              void* d_out, int out_size, void* d_ws, size_t ws_size,
                              hipStream_t stream) {
    const float* rois    = (const float*)d_in[0];
    const float* pbox    = (const float*)d_in[1];
    const float* vfeat   = (const float*)d_in[2];
    const float* fproto  = (const float*)d_in[3];
    const int*   vcoords = (const int*)d_in[4];
    float* out = (float*)d_out;

    // ws layout: v2p | list | cnt(256B) | partial (separate if room, else
    // aliases v2p with NS=2 -- v2p is dead after k_build).
    int*      v2p  = (int*)d_ws;                               // NGRID ints (5.63 MB)
    unsigned* list = (unsigned*)(v2p + NGRID);                 // MROI*GCELLS (2.10 MB)
    int*      cnt  = (int*)(list + MROI * GCELLS);             // 64 ints (256 B slot)
    size_t    base = ((size_t)NGRID + (size_t)MROI * GCELLS) * 4 + 256;
    int NS; float* partial;
    if (ws_size >= base + (size_t)8 * MROI * GCELLS * 4) {
        NS = 8;  partial = (float*)((char*)d_ws + base);       // 16 MB region
    } else if (ws_size >= base + (size_t)4 * MROI * GCELLS * 4) {
        NS = 4;  partial = (float*)((char*)d_ws + base);       // 8 MB region
    } else {
        NS = 2;  partial = (float*)v2p;                        // alias fallback
    }

    hipFuncSetAttribute((const void*)k_dots,
                        hipFuncAttributeMaxDynamicSharedMemorySize, DYN_LDS);

    hipMemsetAsync(v2p, 0xFF, (size_t)NGRID * 4, stream);      // v2p = -1
    k_scatter<<<(NVOX + 255) / 256, 256, 0, stream>>>(vcoords, v2p, cnt);
    k_build  <<<dim3(GCELLS / 256, MROI), 256, 0, stream>>>(rois, v2p, list, cnt);
    k_dots   <<<dim3(NS, MROI), 256, DYN_LDS, stream>>>(vfeat, fproto, list, cnt, partial);
    k_argfin <<<MROI, 256, 0, stream>>>(partial, NS, rois, pbox, out);
}

// Round 8
// 300.545 us; speedup vs baseline: 1.3179x; 1.3179x over previous
//
#include <hip/hip_runtime.h>
#include <stdint.h>

#define GRID_Z 10
#define GRID_Y 400
#define GRID_X 352
#define NGRID (GRID_Z * GRID_Y * GRID_X)   // 1,408,000
#define NVOX 200000
#define CCH 128
#define MROI 64
#define GXD 64
#define GYD 32
#define GZD 4
#define GCELLS 8192                         // GXD*GYD*GZD
#define NTAPS 147                           // 7*7*3
#define FPAD 132                            // feat LDS row pitch (128+4)
#define TROWS 32                            // voxel rows per tile

// Recompute a grid cell's world xyz exactly like the reference (fp32, no fma
// contraction so floor() boundaries match XLA's mul+add evaluation).
__device__ __forceinline__ void cell_xyz(const float* __restrict__ roi, int g,
                                         float& X, float& Y, float& Z) {
#pragma clang fp contract(off)
    int iz = g & 3;
    int iy = (g >> 2) & 31;
    int ix = g >> 7;
    float bx = roi[3] * 2.0f;   // EXTEND on x,y dims
    float by = roi[4] * 2.0f;
    float bz = roi[5];
    float lx = (ix + 0.5f) / 64.0f * bx - bx / 2.0f;
    float ly = (iy + 0.5f) / 32.0f * by - by / 2.0f;
    float lz = (iz + 0.5f) / 4.0f  * bz - bz / 2.0f;
    float c = cosf(roi[6]);
    float s = sinf(roi[6]);
    X = lx * c + ly * (-s) + roi[0];
    Y = lx * s + ly * c    + roi[1];
    Z = lz + roi[2];
}

__global__ void k_scatter(const int* __restrict__ vcoords, int* __restrict__ v2p,
                          int* __restrict__ cnt) {
    int i = blockIdx.x * 256 + threadIdx.x;
    if (blockIdx.x == 0 && threadIdx.x < MROI) cnt[threadIdx.x] = 0;  // fold memset
    if (i >= NVOX) return;
    int z = vcoords[i * 4 + 1];
    int y = vcoords[i * 4 + 2];
    int x = vcoords[i * 4 + 3];
    // Duplicate coords: XLA scatter applies updates in order -> last (max idx) wins.
    atomicMax(&v2p[(z * GRID_Y + y) * GRID_X + x], i);
}

// Per (m, g): map grid cell to voxel index; ballot-compact valid (p,g) pairs
// into a per-ROI list (order nondeterministic; only perturbs fp sum order).
__global__ void k_build(const float* __restrict__ rois, const int* __restrict__ v2p,
                        unsigned* __restrict__ list, int* __restrict__ cnt) {
#pragma clang fp contract(off)
    int g = blockIdx.x * 256 + threadIdx.x;   // [0, GCELLS)
    int m = blockIdx.y;
    int lane = threadIdx.x & 63;
    const float* roi = rois + m * 7;
    float X, Y, Z;
    cell_xyz(roi, g, X, Y, Z);
    float fx = floorf((X - 0.0f)     / 0.05f);
    float fy = floorf((Y - (-40.0f)) / 0.05f);
    float fz = floorf((Z - (-3.0f))  / 0.1f);
    int cx = (int)floorf(fx / 4.0f);
    int cy = (int)floorf(fy / 4.0f);
    int cz = (int)floorf(fz / 4.0f);
    int p = -1;
    if (cz >= 0 && cz < GRID_Z && cy >= 0 && cy < GRID_Y && cx >= 0 && cx < GRID_X)
        p = v2p[(cz * GRID_Y + cy) * GRID_X + cx];
    bool v = p >= 0;
    unsigned long long bal = __ballot(v);
    int nset = __popcll(bal);
    int base = 0;
    if (lane == 0 && nset) base = atomicAdd(&cnt[m], nset);
    base = __shfl(base, 0, 64);
    if (v) {
        int pos = __popcll(bal & ((1ull << lane) - 1ull));
        list[m * GCELLS + base + pos] = ((unsigned)p << 13) | (unsigned)g;
    }
}

// Batched-GEMM dots + LDS scatter (Round-6 measured-best shape, NS=12 grid).
// Block (s, m): private 32 KB LDS score for ROI m; 32-voxel tiles staged in
// LDS; wave w owns taps [40w,40w+40); lane (vi=l&7, ti=(l>>3)&7) computes a
// 4-voxel x 5-tap register tile over K=128. Dots deposit via ds_add_f32;
// epilogue writes the 32 KB partial with plain coalesced stores.
__global__ __launch_bounds__(256) void k_dots(
        const float* __restrict__ vfeat, const float* __restrict__ fproto,
        const unsigned* __restrict__ list, const int* __restrict__ cnt,
        float* __restrict__ partial) {
    __shared__ float    sscore[GCELLS];        // 32 KB
    __shared__ float    sfeat[TROWS * FPAD];   // 16.9 KB
    __shared__ unsigned sg[TROWS];

    const int m    = blockIdx.y;
    const int NS   = gridDim.x;
    const int tid  = threadIdx.x;
    const int w    = tid >> 6;                 // wave 0..3
    const int lane = tid & 63;
    const int vi   = lane & 7;
    const int ti   = (lane >> 3) & 7;
    const int n    = cnt[m];
    const unsigned* lst = list + m * GCELLS;
    const int tbase = w * 40 + ti;             // thread's taps: tbase + 8b, b=0..4

    // hoist tap decomposition (loop-invariant)
    int tkx[5], tky[5], tkz[5], tok[5];
    #pragma unroll
    for (int b = 0; b < 5; ++b) {
        int t = tbase + 8 * b;
        tok[b] = t < NTAPS;
        int tc = tok[b] ? t : (NTAPS - 1);
        int kx  = tc / 21;
        int rem = tc - kx * 21;
        tkx[b] = kx;
        tky[b] = rem / 3;
        tkz[b] = rem - tky[b] * 3;
    }

    {   // zero the private score tile
        float4* s4 = (float4*)sscore;
        #pragma unroll
        for (int i = 0; i < GCELLS / 4 / 256; ++i)
            s4[tid + 256 * i] = make_float4(0.f, 0.f, 0.f, 0.f);
    }

    for (int vt0 = blockIdx.x * TROWS; vt0 < n; vt0 += TROWS * NS) {
        __syncthreads();                       // score-zero / prior deposits done
        {   // stage 32 feat rows: 8 threads per row, 16 floats each
            int r = tid >> 3;                  // row 0..31
            int q = tid & 7;                   // 16-float chunk
            int v = vt0 + r;
            unsigned e = 0xFFFFFFFFu;
            if (v < n) e = lst[v];
            if (q == 0) sg[r] = e;
            if (e != 0xFFFFFFFFu) {
                int p = (int)(e >> 13);
                const float4* src = (const float4*)(vfeat + (size_t)p * CCH) + q * 4;
                float4* drow = (float4*)(sfeat + r * FPAD + q * 16);
                #pragma unroll
                for (int j = 0; j < 4; ++j) drow[j] = src[j];
            }
        }
        __syncthreads();

        float acc[4][5];
        #pragma unroll
        for (int a = 0; a < 4; ++a)
            #pragma unroll
            for (int b = 0; b < 5; ++b) acc[a][b] = 0.0f;

        #pragma unroll 1
        for (int k = 0; k < CCH; k += 4) {
            float4 f[4];
            #pragma unroll
            for (int a = 0; a < 4; ++a)
                f[a] = *(const float4*)&sfeat[(vi + 8 * a) * FPAD + k];
            float4 wv[5];
            #pragma unroll
            for (int b = 0; b < 5; ++b)
                wv[b] = *(const float4*)(fproto + (tbase + (tok[b] ? 8 * b : 0)) * CCH + k);
            #pragma unroll
            for (int a = 0; a < 4; ++a)
                #pragma unroll
                for (int b = 0; b < 5; ++b) {
                    acc[a][b] = fmaf(f[a].x, wv[b].x, acc[a][b]);
                    acc[a][b] = fmaf(f[a].y, wv[b].y, acc[a][b]);
                    acc[a][b] = fmaf(f[a].z, wv[b].z, acc[a][b]);
                    acc[a][b] = fmaf(f[a].w, wv[b].w, acc[a][b]);
                }
        }

        // deposit dots into the private LDS score grid (ds_add_f32 atomics)
        #pragma unroll
        for (int b = 0; b < 5; ++b) {
            if (!tok[b]) continue;
            #pragma unroll
            for (int a = 0; a < 4; ++a) {
                unsigned e = sg[vi + 8 * a];
                if (e == 0xFFFFFFFFu) continue;
                int g  = (int)(e & 8191u);
                int cx = (g >> 7)        - (tkx[b] - 3);
                int cy = ((g >> 2) & 31) - (tky[b] - 3);
                int cz = (g & 3)         - (tkz[b] - 1);
                if ((unsigned)cx < (unsigned)GXD && (unsigned)cy < (unsigned)GYD &&
                    (unsigned)cz < (unsigned)GZD)
                    atomicAdd(&sscore[(cx << 7) | (cy << 2) | cz], acc[a][b]);
            }
        }
    }

    __syncthreads();                           // all waves' deposits done
    {   // coalesced partial writeback (covers every cell -> no global zeroing)
        float* dst = partial + ((size_t)m * NS + blockIdx.x) * GCELLS;
        const float4* s4 = (const float4*)sscore;
        float4* d4 = (float4*)dst;
        #pragma unroll
        for (int i = 0; i < GCELLS / 4 / 256; ++i)
            d4[tid + 256 * i] = s4[tid + 256 * i];
    }
}

// Fused partial-merge + argmax + output write: one block per ROI.
// NS is a compile-time template arg -> the s-loop fully unrolls (NS loads in
// flight instead of a loop-carried serial chain). 1024 threads/block.
template <int NS>
__global__ __launch_bounds__(1024) void k_argfin(
        const float* __restrict__ partial,
        const float* __restrict__ rois,
        const float* __restrict__ pbox,
        float* __restrict__ out) {
    __shared__ unsigned long long red[1024];
    int m = blockIdx.x;
    int tid = threadIdx.x;
    const float* base = partial + (size_t)m * NS * GCELLS;
    unsigned long long bk = 0ull;
    #pragma unroll
    for (int i = 0; i < GCELLS / 1024; ++i) {
        int g = tid + 1024 * i;
        float v = 0.0f;
        #pragma unroll
        for (int s = 0; s < NS; ++s) v += base[s * GCELLS + g];
        unsigned ub  = __float_as_uint(v);
        unsigned key = (ub & 0x80000000u) ? ~ub : (ub | 0x80000000u);  // order-preserving
        unsigned long long pk =
            ((unsigned long long)key << 32) | (unsigned)(GCELLS - 1 - g);  // ties -> smallest g
        bk = bk > pk ? bk : pk;
    }
    red[tid] = bk;
    __syncthreads();
    for (int s = 512; s > 0; s >>= 1) {
        if (tid < s) {
            unsigned long long o = red[tid + s];
            if (o > red[tid]) red[tid] = o;
        }
        __syncthreads();
    }
    if (tid == 0) {
        int g = (GCELLS - 1) - (int)(unsigned)(red[0] & 0xFFFFFFFFu);
        float X, Y, Z;
        cell_xyz(rois + m * 7, g, X, Y, Z);
        out[m * 7 + 0] = X;
        out[m * 7 + 1] = Y;
        out[m * 7 + 2] = Z;
        out[m * 7 + 3] = pbox[3];
        out[m * 7 + 4] = pbox[4];
        out[m * 7 + 5] = pbox[5];
        out[m * 7 + 6] = pbox[6];
    }
}

extern "C" void kernel_launch(void* const* d_in, const int* in_sizes, int n_in,
                              void* d_out, int out_size, void* d_ws, size_t ws_size,
                              hipStream_t stream) {
    const float* rois    = (const float*)d_in[0];
    const float* pbox    = (const float*)d_in[1];
    const float* vfeat   = (const float*)d_in[2];
    const float* fproto  = (const float*)d_in[3];
    const int*   vcoords = (const int*)d_in[4];
    float* out = (float*)d_out;

    // ws layout: v2p | list | cnt(256B) | partial (separate if room, else
    // aliases v2p with NS=2 -- v2p is dead after k_build).
    int*      v2p  = (int*)d_ws;                               // NGRID ints (5.63 MB)
    unsigned* list = (unsigned*)(v2p + NGRID);                 // MROI*GCELLS (2.10 MB)
    int*      cnt  = (int*)(list + MROI * GCELLS);             // 64 ints (256 B slot)
    size_t    base = ((size_t)NGRID + (size_t)MROI * GCELLS) * 4 + 256;
    int NS; float* partial;
    if (ws_size >= base + (size_t)12 * MROI * GCELLS * 4) {
        NS = 12; partial = (float*)((char*)d_ws + base);       // 25.2 MB region
    } else if (ws_size >= base + (size_t)8 * MROI * GCELLS * 4) {
        NS = 8;  partial = (float*)((char*)d_ws + base);       // 16.8 MB region
    } else if (ws_size >= base + (size_t)4 * MROI * GCELLS * 4) {
        NS = 4;  partial = (float*)((char*)d_ws + base);       // 8.4 MB region
    } else {
        NS = 2;  partial = (float*)v2p;                        // alias fallback
    }

    hipMemsetAsync(v2p, 0xFF, (size_t)NGRID * 4, stream);      // v2p = -1
    k_scatter<<<(NVOX + 255) / 256, 256, 0, stream>>>(vcoords, v2p, cnt);
    k_build  <<<dim3(GCELLS / 256, MROI), 256, 0, stream>>>(rois, v2p, list, cnt);
    k_dots   <<<dim3(NS, MROI), 256, 0, stream>>>(vfeat, fproto, list, cnt, partial);
    if (NS == 12)      k_argfin<12><<<MROI, 1024, 0, stream>>>(partial, rois, pbox, out);
    else if (NS == 8)  k_argfin<8> <<<MROI, 1024, 0, stream>>>(partial, rois, pbox, out);
    else if (NS == 4)  k_argfin<4> <<<MROI, 1024, 0, stream>>>(partial, rois, pbox, out);
    else               k_argfin<2> <<<MROI, 1024, 0, stream>>>(partial, rois, pbox, out);
}

// Round 9
// 299.556 us; speedup vs baseline: 1.3222x; 1.0033x over previous
//
#include <hip/hip_runtime.h>
#include <hip/hip_cooperative_groups.h>
#include <stdint.h>

namespace cg = cooperative_groups;

#define GRID_Z 10
#define GRID_Y 400
#define GRID_X 352
#define NGRID (GRID_Z * GRID_Y * GRID_X)   // 1,408,000
#define NVOX 200000
#define CCH 128
#define MROI 64
#define GXD 64
#define GYD 32
#define GZD 4
#define GCELLS 8192                         // GXD*GYD*GZD
#define NTAPS 147                           // 7*7*3
#define FPAD 132                            // feat LDS row pitch (128+4)
#define TROWS 32                            // voxel rows per tile
#define NS12 12                             // partial slices per ROI
#define NBLK (NS12 * MROI)                  // 768 = 3 blocks/CU x 256 CUs
#define NTH  (NBLK * 256)                   // 196608 threads
#define CHUNK ((GCELLS + NS12 - 1) / NS12)  // 683 cells per merge block

// Recompute a grid cell's world xyz exactly like the reference (fp32, no fma
// contraction so floor() boundaries match XLA's mul+add evaluation).
__device__ __forceinline__ void cell_xyz(const float* __restrict__ roi, int g,
                                         float& X, float& Y, float& Z) {
#pragma clang fp contract(off)
    int iz = g & 3;
    int iy = (g >> 2) & 31;
    int ix = g >> 7;
    float bx = roi[3] * 2.0f;   // EXTEND on x,y dims
    float by = roi[4] * 2.0f;
    float bz = roi[5];
    float lx = (ix + 0.5f) / 64.0f * bx - bx / 2.0f;
    float ly = (iy + 0.5f) / 32.0f * by - by / 2.0f;
    float lz = (iz + 0.5f) / 4.0f  * bz - bz / 2.0f;
    float c = cosf(roi[6]);
    float s = sinf(roi[6]);
    X = lx * c + ly * (-s) + roi[0];
    Y = lx * s + ly * c    + roi[1];
    Z = lz + roi[2];
}

__device__ __forceinline__ int cell_to_pidx(const float* __restrict__ roi, int g,
                                            const int* __restrict__ v2p) {
#pragma clang fp contract(off)
    float X, Y, Z;
    cell_xyz(roi, g, X, Y, Z);
    float fx = floorf((X - 0.0f)     / 0.05f);
    float fy = floorf((Y - (-40.0f)) / 0.05f);
    float fz = floorf((Z - (-3.0f))  / 0.1f);
    int cx = (int)floorf(fx / 4.0f);
    int cy = (int)floorf(fy / 4.0f);
    int cz = (int)floorf(fz / 4.0f);
    int p = -1;
    if (cz >= 0 && cz < GRID_Z && cy >= 0 && cy < GRID_Y && cx >= 0 && cx < GRID_X)
        p = v2p[(cz * GRID_Y + cy) * GRID_X + cx];
    return p;
}

// ---------------- single cooperative mega-kernel ----------------
// 768 blocks x 256 threads, phases split by grid.sync():
// P0 init -> P1 scatter -> P2 build -> P3 dots -> P4 merge+argmax -> P5 out.
__global__ __launch_bounds__(256) void k_mega(
        const float* __restrict__ rois, const float* __restrict__ pbox,
        const float* __restrict__ vfeat, const float* __restrict__ fproto,
        const int* __restrict__ vcoords,
        int* __restrict__ v2p, unsigned* __restrict__ list, int* __restrict__ cnt,
        float* __restrict__ partial, unsigned long long* __restrict__ best,
        float* __restrict__ out) {
    __shared__ float    sscore[GCELLS];        // 32 KB (P3; aliased as u64[256] in P4)
    __shared__ float    sfeat[TROWS * FPAD];   // 16.9 KB
    __shared__ unsigned sg[TROWS];

    cg::grid_group grid = cg::this_grid();
    const int tid  = threadIdx.x;
    const int gtid = blockIdx.x * 256 + tid;
    const int lane = tid & 63;

    // ---- P0: init ----
    for (int i = gtid; i < NGRID; i += NTH) v2p[i] = -1;
    if (gtid < MROI) { cnt[gtid] = 0; best[gtid] = 0ull; }
    grid.sync();

    // ---- P1: voxel scatter (last duplicate wins via atomicMax) ----
    for (int i = gtid; i < NVOX; i += NTH) {
        int z = vcoords[i * 4 + 1];
        int y = vcoords[i * 4 + 2];
        int x = vcoords[i * 4 + 3];
        atomicMax(&v2p[(z * GRID_Y + y) * GRID_X + x], i);
    }
    grid.sync();

    // ---- P2: build per-ROI compact (p,g) lists ----
    // waves stay m-uniform: 8192 % 64 == 0 and lanes are gtid-consecutive.
    for (int idx = gtid; idx < MROI * GCELLS; idx += NTH) {
        int m = idx >> 13;
        int g = idx & 8191;
        int p = cell_to_pidx(rois + m * 7, g, v2p);
        bool v = p >= 0;
        unsigned long long bal = __ballot(v);
        int nset = __popcll(bal);
        int base = 0;
        if (lane == 0 && nset) base = atomicAdd(&cnt[m], nset);
        base = __shfl(base, 0, 64);
        if (v) {
            int pos = __popcll(bal & ((1ull << lane) - 1ull));
            list[m * GCELLS + base + pos] = ((unsigned)p << 13) | (unsigned)g;
        }
    }
    grid.sync();

    // ---- P3: batched-GEMM dots + LDS scatter (R8 measured-best shape) ----
    {
        const int m = blockIdx.x & 63;
        const int s = blockIdx.x >> 6;         // slice 0..11
        const int w    = tid >> 6;             // wave 0..3
        const int vi   = lane & 7;
        const int ti   = (lane >> 3) & 7;
        const int n    = cnt[m];
        const unsigned* lst = list + m * GCELLS;
        const int tbase = w * 40 + ti;         // taps: tbase + 8b, b=0..4

        int tkx[5], tky[5], tkz[5], tok[5];
        #pragma unroll
        for (int b = 0; b < 5; ++b) {
            int t = tbase + 8 * b;
            tok[b] = t < NTAPS;
            int tc = tok[b] ? t : (NTAPS - 1);
            int kx  = tc / 21;
            int rem = tc - kx * 21;
            tkx[b] = kx;
            tky[b] = rem / 3;
            tkz[b] = rem - tky[b] * 3;
        }

        {   // zero the private score tile
            float4* s4 = (float4*)sscore;
            #pragma unroll
            for (int i = 0; i < GCELLS / 4 / 256; ++i)
                s4[tid + 256 * i] = make_float4(0.f, 0.f, 0.f, 0.f);
        }

        for (int vt0 = s * TROWS; vt0 < n; vt0 += TROWS * NS12) {
            __syncthreads();                   // score-zero / prior deposits done
            {   // stage 32 feat rows: 8 threads per row, 16 floats each
                int r = tid >> 3;
                int q = tid & 7;
                int v = vt0 + r;
                unsigned e = 0xFFFFFFFFu;
                if (v < n) e = lst[v];
                if (q == 0) sg[r] = e;
                if (e != 0xFFFFFFFFu) {
                    int p = (int)(e >> 13);
                    const float4* src = (const float4*)(vfeat + (size_t)p * CCH) + q * 4;
                    float4* drow = (float4*)(sfeat + r * FPAD + q * 16);
                    #pragma unroll
                    for (int j = 0; j < 4; ++j) drow[j] = src[j];
                }
            }
            __syncthreads();

            float acc[4][5];
            #pragma unroll
            for (int a = 0; a < 4; ++a)
                #pragma unroll
                for (int b = 0; b < 5; ++b) acc[a][b] = 0.0f;

            #pragma unroll 1
            for (int k = 0; k < CCH; k += 4) {
                float4 f[4];
                #pragma unroll
                for (int a = 0; a < 4; ++a)
                    f[a] = *(const float4*)&sfeat[(vi + 8 * a) * FPAD + k];
                float4 wv[5];
                #pragma unroll
                for (int b = 0; b < 5; ++b)
                    wv[b] = *(const float4*)(fproto + (tbase + (tok[b] ? 8 * b : 0)) * CCH + k);
                #pragma unroll
                for (int a = 0; a < 4; ++a)
                    #pragma unroll
                    for (int b = 0; b < 5; ++b) {
                        acc[a][b] = fmaf(f[a].x, wv[b].x, acc[a][b]);
                        acc[a][b] = fmaf(f[a].y, wv[b].y, acc[a][b]);
                        acc[a][b] = fmaf(f[a].z, wv[b].z, acc[a][b]);
                        acc[a][b] = fmaf(f[a].w, wv[b].w, acc[a][b]);
                    }
            }

            #pragma unroll
            for (int b = 0; b < 5; ++b) {
                if (!tok[b]) continue;
                #pragma unroll
                for (int a = 0; a < 4; ++a) {
                    unsigned e = sg[vi + 8 * a];
                    if (e == 0xFFFFFFFFu) continue;
                    int g  = (int)(e & 8191u);
                    int cx = (g >> 7)        - (tkx[b] - 3);
                    int cy = ((g >> 2) & 31) - (tky[b] - 3);
                    int cz = (g & 3)         - (tkz[b] - 1);
                    if ((unsigned)cx < (unsigned)GXD && (unsigned)cy < (unsigned)GYD &&
                        (unsigned)cz < (unsigned)GZD)
                        atomicAdd(&sscore[(cx << 7) | (cy << 2) | cz], acc[a][b]);
                }
            }
        }

        __syncthreads();                       // all waves' deposits done
        {   // coalesced partial writeback (covers every cell)
            float* dst = partial + ((size_t)m * NS12 + s) * GCELLS;
            const float4* s4 = (const float4*)sscore;
            float4* d4 = (float4*)dst;
            #pragma unroll
            for (int i = 0; i < GCELLS / 4 / 256; ++i)
                d4[tid + 256 * i] = s4[tid + 256 * i];
        }
    }
    grid.sync();

    // ---- P4: merge partials + argmax (12 blocks per ROI) ----
    {
        int m = blockIdx.x & 63;
        int s = blockIdx.x >> 6;
        const float* basep = partial + (size_t)m * NS12 * GCELLS;
        int c0 = s * CHUNK;
        int c1 = c0 + CHUNK < GCELLS ? c0 + CHUNK : GCELLS;
        unsigned long long bk = 0ull;
        for (int c = c0 + tid; c < c1; c += 256) {
            float v = 0.0f;
            #pragma unroll
            for (int q = 0; q < NS12; ++q) v += basep[q * GCELLS + c];
            unsigned ub  = __float_as_uint(v);
            unsigned key = (ub & 0x80000000u) ? ~ub : (ub | 0x80000000u);  // order-preserving
            unsigned long long pk =
                ((unsigned long long)key << 32) | (unsigned)(GCELLS - 1 - c);  // ties -> smallest g
            bk = bk > pk ? bk : pk;
        }
        __syncthreads();                       // P3 writeback reads of sscore done
        unsigned long long* red = reinterpret_cast<unsigned long long*>(sscore);
        red[tid] = bk;
        __syncthreads();
        for (int st = 128; st > 0; st >>= 1) {
            if (tid < st) {
                unsigned long long o = red[tid + st];
                if (o > red[tid]) red[tid] = o;
            }
            __syncthreads();
        }
        if (tid == 0) atomicMax(&best[m], red[0]);
    }
    grid.sync();

    // ---- P5: write output ----
    if (blockIdx.x == 0 && tid < MROI) {
        int m = tid;
        int g = (GCELLS - 1) - (int)(unsigned)(best[m] & 0xFFFFFFFFu);
        float X, Y, Z;
        cell_xyz(rois + m * 7, g, X, Y, Z);
        out[m * 7 + 0] = X;
        out[m * 7 + 1] = Y;
        out[m * 7 + 2] = Z;
        out[m * 7 + 3] = pbox[3];
        out[m * 7 + 4] = pbox[4];
        out[m * 7 + 5] = pbox[5];
        out[m * 7 + 6] = pbox[6];
    }
}

// ---------------- fallback path (R8 kernels, used if coop unavailable) ----------------
__global__ void k_scatter(const int* __restrict__ vcoords, int* __restrict__ v2p,
                          int* __restrict__ cnt) {
    int i = blockIdx.x * 256 + threadIdx.x;
    if (blockIdx.x == 0 && threadIdx.x < MROI) cnt[threadIdx.x] = 0;
    if (i >= NVOX) return;
    int z = vcoords[i * 4 + 1];
    int y = vcoords[i * 4 + 2];
    int x = vcoords[i * 4 + 3];
    atomicMax(&v2p[(z * GRID_Y + y) * GRID_X + x], i);
}

__global__ void k_build(const float* __restrict__ rois, const int* __restrict__ v2p,
                        unsigned* __restrict__ list, int* __restrict__ cnt) {
    int g = blockIdx.x * 256 + threadIdx.x;
    int m = blockIdx.y;
    int lane = threadIdx.x & 63;
    int p = cell_to_pidx(rois + m * 7, g, v2p);
    bool v = p >= 0;
    unsigned long long bal = __ballot(v);
    int nset = __popcll(bal);
    int base = 0;
    if (lane == 0 && nset) base = atomicAdd(&cnt[m], nset);
    base = __shfl(base, 0, 64);
    if (v) {
        int pos = __popcll(bal & ((1ull << lane) - 1ull));
        list[m * GCELLS + base + pos] = ((unsigned)p << 13) | (unsigned)g;
    }
}

__global__ __launch_bounds__(256) void k_dots(
        const float* __restrict__ vfeat, const float* __restrict__ fproto,
        const unsigned* __restrict__ list, const int* __restrict__ cnt,
        float* __restrict__ partial) {
    __shared__ float    sscore[GCELLS];
    __shared__ float    sfeat[TROWS * FPAD];
    __shared__ unsigned sg[TROWS];

    const int m    = blockIdx.y;
    const int NSd  = gridDim.x;
    const int tid  = threadIdx.x;
    const int w    = tid >> 6;
    const int lane = tid & 63;
    const int vi   = lane & 7;
    const int ti   = (lane >> 3) & 7;
    const int n    = cnt[m];
    const unsigned* lst = list + m * GCELLS;
    const int tbase = w * 40 + ti;

    int tkx[5], tky[5], tkz[5], tok[5];
    #pragma unroll
    for (int b = 0; b < 5; ++b) {
        int t = tbase + 8 * b;
        tok[b] = t < NTAPS;
        int tc = tok[b] ? t : (NTAPS - 1);
        int kx  = tc / 21;
        int rem = tc - kx * 21;
        tkx[b] = kx; tky[b] = rem / 3; tkz[b] = rem - tky[b] * 3;
    }
    {
        float4* s4 = (float4*)sscore;
        #pragma unroll
        for (int i = 0; i < GCELLS / 4 / 256; ++i)
            s4[tid + 256 * i] = make_float4(0.f, 0.f, 0.f, 0.f);
    }
    for (int vt0 = blockIdx.x * TROWS; vt0 < n; vt0 += TROWS * NSd) {
        __syncthreads();
        {
            int r = tid >> 3, q = tid & 7, v = vt0 + r;
            unsigned e = 0xFFFFFFFFu;
            if (v < n) e = lst[v];
            if (q == 0) sg[r] = e;
            if (e != 0xFFFFFFFFu) {
                int p = (int)(e >> 13);
                const float4* src = (const float4*)(vfeat + (size_t)p * CCH) + q * 4;
                float4* drow = (float4*)(sfeat + r * FPAD + q * 16);
                #pragma unroll
                for (int j = 0; j < 4; ++j) drow[j] = src[j];
            }
        }
        __syncthreads();
        float acc[4][5];
        #pragma unroll
        for (int a = 0; a < 4; ++a)
            #pragma unroll
            for (int b = 0; b < 5; ++b) acc[a][b] = 0.0f;
        #pragma unroll 1
        for (int k = 0; k < CCH; k += 4) {
            float4 f[4];
            #pragma unroll
            for (int a = 0; a < 4; ++a)
                f[a] = *(const float4*)&sfeat[(vi + 8 * a) * FPAD + k];
            float4 wv[5];
            #pragma unroll
            for (int b = 0; b < 5; ++b)
                wv[b] = *(const float4*)(fproto + (tbase + (tok[b] ? 8 * b : 0)) * CCH + k);
            #pragma unroll
            for (int a = 0; a < 4; ++a)
                #pragma unroll
                for (int b = 0; b < 5; ++b) {
                    acc[a][b] = fmaf(f[a].x, wv[b].x, acc[a][b]);
                    acc[a][b] = fmaf(f[a].y, wv[b].y, acc[a][b]);
                    acc[a][b] = fmaf(f[a].z, wv[b].z, acc[a][b]);
                    acc[a][b] = fmaf(f[a].w, wv[b].w, acc[a][b]);
                }
        }
        #pragma unroll
        for (int b = 0; b < 5; ++b) {
            if (!tok[b]) continue;
            #pragma unroll
            for (int a = 0; a < 4; ++a) {
                unsigned e = sg[vi + 8 * a];
                if (e == 0xFFFFFFFFu) continue;
                int g  = (int)(e & 8191u);
                int cx = (g >> 7)        - (tkx[b] - 3);
                int cy = ((g >> 2) & 31) - (tky[b] - 3);
                int cz = (g & 3)         - (tkz[b] - 1);
                if ((unsigned)cx < (unsigned)GXD && (unsigned)cy < (unsigned)GYD &&
                    (unsigned)cz < (unsigned)GZD)
                    atomicAdd(&sscore[(cx << 7) | (cy << 2) | cz], acc[a][b]);
            }
        }
    }
    __syncthreads();
    {
        float* dst = partial + ((size_t)m * NSd + blockIdx.x) * GCELLS;
        const float4* s4 = (const float4*)sscore;
        float4* d4 = (float4*)dst;
        #pragma unroll
        for (int i = 0; i < GCELLS / 4 / 256; ++i)
            d4[tid + 256 * i] = s4[tid + 256 * i];
    }
}

template <int NS>
__global__ __launch_bounds__(1024) void k_argfin(
        const float* __restrict__ partial, const float* __restrict__ rois,
        const float* __restrict__ pbox, float* __restrict__ out) {
    __shared__ unsigned long long red[1024];
    int m = blockIdx.x;
    int tid = threadIdx.x;
    const float* base = partial + (size_t)m * NS * GCELLS;
    unsigned long long bk = 0ull;
    #pragma unroll
    for (int i = 0; i < GCELLS / 1024; ++i) {
        int g = tid + 1024 * i;
        float v = 0.0f;
        #pragma unroll
        for (int s = 0; s < NS; ++s) v += base[s * GCELLS + g];
        unsigned ub  = __float_as_uint(v);
        unsigned key = (ub & 0x80000000u) ? ~ub : (ub | 0x80000000u);
        unsigned long long pk =
            ((unsigned long long)key << 32) | (unsigned)(GCELLS - 1 - g);
        bk = bk > pk ? bk : pk;
    }
    red[tid] = bk;
    __syncthreads();
    for (int s = 512; s > 0; s >>= 1) {
        if (tid < s) {
            unsigned long long o = red[tid + s];
            if (o > red[tid]) red[tid] = o;
        }
        __syncthreads();
    }
    if (tid == 0) {
        int g = (GCELLS - 1) - (int)(unsigned)(red[0] & 0xFFFFFFFFu);
        float X, Y, Z;
        cell_xyz(rois + m * 7, g, X, Y, Z);
        out[m * 7 + 0] = X;
        out[m * 7 + 1] = Y;
        out[m * 7 + 2] = Z;
        out[m * 7 + 3] = pbox[3];
        out[m * 7 + 4] = pbox[4];
        out[m * 7 + 5] = pbox[5];
        out[m * 7 + 6] = pbox[6];
    }
}

extern "C" void kernel_launch(void* const* d_in, const int* in_sizes, int n_in,
                              void* d_out, int out_size, void* d_ws, size_t ws_size,
                              hipStream_t stream) {
    const float* rois    = (const float*)d_in[0];
    const float* pbox    = (const float*)d_in[1];
    const float* vfeat   = (const float*)d_in[2];
    const float* fproto  = (const float*)d_in[3];
    const int*   vcoords = (const int*)d_in[4];
    float* out = (float*)d_out;

    // ws layout: v2p | list | cnt(256B) | partial (12 slices) | best
    int*      v2p  = (int*)d_ws;                               // NGRID ints
    unsigned* list = (unsigned*)(v2p + NGRID);                 // MROI*GCELLS
    int*      cnt  = (int*)(list + MROI * GCELLS);             // 64 ints (256 B slot)
    float*    partial = (float*)((char*)cnt + 256);            // 12*MROI*GCELLS floats
    unsigned long long* best =
        (unsigned long long*)(partial + (size_t)NS12 * MROI * GCELLS);
    size_t need = (size_t)((char*)(best + MROI) - (char*)d_ws);

    // deterministic decision: cooperative mega-kernel if it fits & is co-resident
    int maxb = 0;
    hipError_t oe = hipOccupancyMaxActiveBlocksPerMultiprocessor(&maxb, k_mega, 256, 0);
    if (oe == hipSuccess && maxb >= 3 && ws_size >= need) {
        void* args[] = { (void*)&rois, (void*)&pbox, (void*)&vfeat, (void*)&fproto,
                         (void*)&vcoords, (void*)&v2p, (void*)&list, (void*)&cnt,
                         (void*)&partial, (void*)&best, (void*)&out };
        hipError_t e = hipLaunchCooperativeKernel((const void*)k_mega, dim3(NBLK),
                                                  dim3(256), args, 0, stream);
        if (e == hipSuccess) return;
    }

    // ---- fallback: R8 multi-launch path ----
    size_t base = ((size_t)NGRID + (size_t)MROI * GCELLS) * 4 + 256;
    int NS; float* fpartial;
    if (ws_size >= base + (size_t)12 * MROI * GCELLS * 4) {
        NS = 12; fpartial = (float*)((char*)d_ws + base);
    } else if (ws_size >= base + (size_t)8 * MROI * GCELLS * 4) {
        NS = 8;  fpartial = (float*)((char*)d_ws + base);
    } else if (ws_size >= base + (size_t)4 * MROI * GCELLS * 4) {
        NS = 4;  fpartial = (float*)((char*)d_ws + base);
    } else {
        NS = 2;  fpartial = (float*)v2p;
    }
    hipMemsetAsync(v2p, 0xFF, (size_t)NGRID * 4, stream);
    k_scatter<<<(NVOX + 255) / 256, 256, 0, stream>>>(vcoords, v2p, cnt);
    k_build  <<<dim3(GCELLS / 256, MROI), 256, 0, stream>>>(rois, v2p, list, cnt);
    k_dots   <<<dim3(NS, MROI), 256, 0, stream>>>(vfeat, fproto, list, cnt, fpartial);
    if (NS == 12)      k_argfin<12><<<MROI, 1024, 0, stream>>>(fpartial, rois, pbox, out);
    else if (NS == 8)  k_argfin<8> <<<MROI, 1024, 0, stream>>>(fpartial, rois, pbox, out);
    else if (NS == 4)  k_argfin<4> <<<MROI, 1024, 0, stream>>>(fpartial, rois, pbox, out);
    else               k_argfin<2> <<<MROI, 1024, 0, stream>>>(fpartial, rois, pbox, out);
}